// Round 2
// baseline (629.445 us; speedup 1.0000x reference)
//
#include <hip/hip_runtime.h>

#define B_     4
#define N_     11
#define D_     589824L     // 64*96*96
#define NPAIR  66          // upper-tri incl. diagonal
#define NCHUNK 3
#define CP     22          // pairs per chunk
#define TPB    256
#define ITER   4           // floats per block = TPB*4*ITER = 4096; 589824/4096 = 144 blocks/batch

__host__ __device__ constexpr int pair_i(int p) {
    int i = 0, cnt = N_;
    while (p >= cnt) { p -= cnt; --cnt; ++i; }
    return i;
}
__host__ __device__ constexpr int pair_j(int p) {
    int i = 0, cnt = N_;
    while (p >= cnt) { p -= cnt; --cnt; ++i; }
    return i + p;
}
__host__ __device__ constexpr bool row_used(int chunk, int m) {
    for (int q = 0; q < CP; ++q) {
        const int p = chunk * CP + q;
        if (pair_i(p) == m || pair_j(p) == m) return true;
    }
    return false;
}

// ---------------------------------------------------------------------------
// Pass 1: pairwise reductions, pair-chunked over blockIdx.z so per-thread
// accumulator count is 44 (not 132) -> no scratch spill, 4 waves/SIMD.
// ---------------------------------------------------------------------------
template <int CHUNK>
__device__ void reduce_body(const float* __restrict__ xb, long base, int b, int t,
                            double* __restrict__ e2ws, double* __restrict__ e1ws) {
    float acc2[CP];
    float acc1[CP];
#pragma unroll
    for (int q = 0; q < CP; ++q) { acc2[q] = 0.f; acc1[q] = 0.f; }

#pragma unroll 1
    for (int k = 0; k < ITER; ++k) {
        const long d = base + (long)k * (TPB * 4);
        float4 v[N_];
#pragma unroll
        for (int m = 0; m < N_; ++m)
            if (row_used(CHUNK, m))   // constexpr-folded after unroll
                v[m] = *reinterpret_cast<const float4*>(xb + (long)m * D_ + d);

#pragma unroll
        for (int q = 0; q < CP; ++q) {
            const int i = pair_i(CHUNK * CP + q);
            const int j = pair_j(CHUNK * CP + q);
            acc2[q] += v[i].x * v[j].x + v[i].y * v[j].y +
                       v[i].z * v[j].z + v[i].w * v[j].w;
            if (i != j) {
                acc1[q] += fabsf(v[i].x - v[j].x) + fabsf(v[i].y - v[j].y) +
                           fabsf(v[i].z - v[j].z) + fabsf(v[i].w - v[j].w);
            }
        }
    }

    // intra-wave shuffle reduce, then cross-wave via LDS
    __shared__ float red2[TPB / 64][CP];
    __shared__ float red1[TPB / 64][CP];
    const int wave = t >> 6, lane = t & 63;
#pragma unroll
    for (int q = 0; q < CP; ++q) {
        float s2 = acc2[q], s1 = acc1[q];
#pragma unroll
        for (int off = 32; off > 0; off >>= 1) {
            s2 += __shfl_down(s2, off, 64);
            s1 += __shfl_down(s1, off, 64);
        }
        if (lane == 0) { red2[wave][q] = s2; red1[wave][q] = s1; }
    }
    __syncthreads();
    if (t < CP) {
        float s2 = 0.f, s1 = 0.f;
#pragma unroll
        for (int w = 0; w < TPB / 64; ++w) { s2 += red2[w][t]; s1 += red1[w][t]; }
        atomicAdd(&e2ws[b * NPAIR + CHUNK * CP + t], (double)s2);
        atomicAdd(&e1ws[b * NPAIR + CHUNK * CP + t], (double)s1);
    }
}

__global__ __launch_bounds__(TPB, 4) void reduce_kernel(const float* __restrict__ x,
                                                        double* __restrict__ e2ws,
                                                        double* __restrict__ e1ws) {
    const int b = blockIdx.y;
    const int t = threadIdx.x;
    const long base = (long)blockIdx.x * (TPB * 4 * ITER) + (long)t * 4;
    const float* xb = x + (long)b * N_ * D_;
    switch (blockIdx.z) {
        case 0:  reduce_body<0>(xb, base, b, t, e2ws, e1ws); break;
        case 1:  reduce_body<1>(xb, base, b, t, e2ws, e1ws); break;
        default: reduce_body<2>(xb, base, b, t, e2ws, e1ws); break;
    }
}

// ---------------------------------------------------------------------------
// Pass 2: energy = e1*e2 (symmetric); attention = softmax(-energy) per row;
// M[n,m] = gamma*attention[n,m] + (n==m).
// ---------------------------------------------------------------------------
__global__ __launch_bounds__(128) void attn_kernel(const double* __restrict__ e2ws,
                                                   const double* __restrict__ e1ws,
                                                   const float* __restrict__ gamma,
                                                   float* __restrict__ Mws) {
    const int b = blockIdx.x;
    const int t = threadIdx.x;
    __shared__ double E[N_][N_];
    if (t < NPAIR) {
        int rem = t, i = 0, cnt = N_;
        while (rem >= cnt) { rem -= cnt; --cnt; ++i; }
        const int j = i + rem;
        const double e = e1ws[b * NPAIR + t] * e2ws[b * NPAIR + t];
        E[i][j] = e;
        E[j][i] = e;
    }
    __syncthreads();
    if (t < N_) {
        const int i = t;
        double mn = E[i][0];
#pragma unroll
        for (int j = 1; j < N_; ++j) mn = fmin(mn, E[i][j]);
        double ex[N_], s = 0.0;
#pragma unroll
        for (int j = 0; j < N_; ++j) { ex[j] = exp(mn - E[i][j]); s += ex[j]; }
        const float g = gamma[0];
        const double inv = 1.0 / s;
#pragma unroll
        for (int j = 0; j < N_; ++j) {
            float m = (float)(ex[j] * inv) * g + (i == j ? 1.0f : 0.0f);
            Mws[(b * N_ + i) * N_ + j] = m;
        }
    }
}

// ---------------------------------------------------------------------------
// Pass 3: out[b,n,d] = sum_m M[b][n][m] * x[b,m,d]   (gamma & +x folded into M)
// ---------------------------------------------------------------------------
__global__ __launch_bounds__(TPB) void apply_kernel(const float* __restrict__ x,
                                                    const float* __restrict__ Mws,
                                                    float* __restrict__ out) {
    const int b = blockIdx.y;
    const int t = threadIdx.x;
    __shared__ float M[N_ * N_];
    if (t < N_ * N_) M[t] = Mws[b * N_ * N_ + t];
    __syncthreads();

    const long d = (long)blockIdx.x * (TPB * 4) + (long)t * 4;
    const float* xb = x + (long)b * N_ * D_;
    float* ob = out + (long)b * N_ * D_;

    float4 v[N_];
#pragma unroll
    for (int m = 0; m < N_; ++m)
        v[m] = *reinterpret_cast<const float4*>(xb + (long)m * D_ + d);

#pragma unroll
    for (int n = 0; n < N_; ++n) {
        float4 o = make_float4(0.f, 0.f, 0.f, 0.f);
#pragma unroll
        for (int m = 0; m < N_; ++m) {
            const float w = M[n * N_ + m];
            o.x += w * v[m].x;
            o.y += w * v[m].y;
            o.z += w * v[m].z;
            o.w += w * v[m].w;
        }
        *reinterpret_cast<float4*>(ob + (long)n * D_ + d) = o;
    }
}

// ---------------------------------------------------------------------------
extern "C" void kernel_launch(void* const* d_in, const int* in_sizes, int n_in,
                              void* d_out, int out_size, void* d_ws, size_t ws_size,
                              hipStream_t stream) {
    const float* x     = (const float*)d_in[0];
    const float* gamma = (const float*)d_in[1];
    float* out         = (float*)d_out;

    double* e2ws = (double*)d_ws;
    double* e1ws = e2ws + B_ * NPAIR;
    float*  Mws  = (float*)(e1ws + B_ * NPAIR);

    hipMemsetAsync(d_ws, 0, (size_t)(2 * B_ * NPAIR) * sizeof(double), stream);

    dim3 gridA(D_ / (TPB * 4 * ITER), B_, NCHUNK);   // (144, 4, 3)
    reduce_kernel<<<gridA, TPB, 0, stream>>>(x, e2ws, e1ws);

    attn_kernel<<<B_, 128, 0, stream>>>(e2ws, e1ws, gamma, Mws);

    dim3 gridC(D_ / (TPB * 4), B_);                  // (576, 4)
    apply_kernel<<<gridC, TPB, 0, stream>>>(x, Mws, out);
}